// Round 1
// baseline (731.654 us; speedup 1.0000x reference)
//
#include <hip/hip_runtime.h>

// CRF forward (log-partition) on MI355X.
// B=128 blocks (one per batch), 512 threads (one per label row).
// Linear-space rescaled forward algorithm:
//   E = exp(trans - T) resident in VGPRs (cols 0..383, f16x2) + LDS (cols 384..511, f16, swizzled)
//   per step: s_i = dot(E_row_i, y) [v_dot2_f32_f16, f32 accum]; v = s*exp(logit);
//             c = max(v); y = v/c (f16); r += T + log(c)
//   result: out[b] = r + T + log(sum_i y_i * exp(trans[stop,i] - T))

typedef _Float16 h2 __attribute__((ext_vector_type(2)));

#define NB 128
#define NS 256
#define NL 512

#define SMEM_ELDS_BYTES (NL * 16 * 16)            // 512 rows * 16 chunks * 16B = 131072
#define SMEM_Y_OFF      SMEM_ELDS_BYTES
#define SMEM_RED_OFF    (SMEM_ELDS_BYTES + NL * 2)
#define SMEM_TOTAL      (SMEM_RED_OFF + 64)

__device__ __forceinline__ float dot2acc(unsigned int e, unsigned int y, float acc) {
#if __has_builtin(__builtin_amdgcn_fdot2)
    return __builtin_amdgcn_fdot2(__builtin_bit_cast(h2, e),
                                  __builtin_bit_cast(h2, y), acc, false);
#else
    h2 eh = __builtin_bit_cast(h2, e);
    h2 yh = __builtin_bit_cast(h2, y);
    return acc + (float)eh[0] * (float)yh[0] + (float)eh[1] * (float)yh[1];
#endif
}

__device__ __forceinline__ unsigned int pk2(float a, float b) {
    h2 h;
    h[0] = (_Float16)a;
    h[1] = (_Float16)b;
    return __builtin_bit_cast(unsigned int, h);
}

__global__ __launch_bounds__(512, 2) void crf_fwd_kernel(
    const float* __restrict__ logits,   // [128,256,512] f32
    const int*   __restrict__ lens_raw, // [128] i32 or i64 (autodetect)
    const float* __restrict__ trans,    // [512,512] f32, trans[i*512+j] = score j->i
    float* __restrict__ out)            // [128] f32
{
    extern __shared__ char smem[];
    uint4*          e_lds = (uint4*)smem;                       // [512][16] f16x8 chunks
    unsigned short* y_sh  = (unsigned short*)(smem + SMEM_Y_OFF); // [512] f16
    float*          red   = (float*)(smem + SMEM_RED_OFF);      // [8]

    const int b    = blockIdx.x;
    const int i    = threadIdx.x;   // label row 0..511
    const int lane = i & 63;
    const int wid  = i >> 6;
    const int swz  = i & 15;

    // lens: detect int32 vs int64 (values are in [1,256], so high words of i64 are 0)
    int len;
    {
        int s1 = lens_raw[1];
        len = (s1 == 0) ? lens_raw[2 * b] : lens_raw[b];
        len = min(max(len, 0), NS);
    }

    const float4* trow4 = (const float4*)(trans + (size_t)i * NL);

    // ---- phase 0: T = global max of transitions (block-local, block-consistent) ----
    float m = -3.4e38f;
    for (int c = 0; c < NL / 4; ++c) {
        float4 v = trow4[c];
        m = fmaxf(m, fmaxf(fmaxf(v.x, v.y), fmaxf(v.z, v.w)));
    }
    #pragma unroll
    for (int off = 32; off; off >>= 1) m = fmaxf(m, __shfl_xor(m, off));
    if (lane == 0) red[wid] = m;
    __syncthreads();
    float T = red[0];
    #pragma unroll
    for (int k = 1; k < 8; ++k) T = fmaxf(T, red[k]);
    __syncthreads();

    // ---- phase 1: build E = exp(trans - T): cols 0..383 -> VGPRs, 384..511 -> LDS ----
    unsigned int Ereg[192];          // 384 cols as packed f16x2, fully unrolled indexing
    #pragma unroll
    for (int c = 0; c < 96; ++c) {
        float4 v = trow4[c];
        Ereg[2 * c]     = pk2(__expf(v.x - T), __expf(v.y - T));
        Ereg[2 * c + 1] = pk2(__expf(v.z - T), __expf(v.w - T));
    }
    #pragma unroll
    for (int c = 0; c < 16; ++c) {
        float4 a = trow4[96 + 2 * c];
        float4 d = trow4[97 + 2 * c];
        uint4 w;
        w.x = pk2(__expf(a.x - T), __expf(a.y - T));
        w.y = pk2(__expf(a.z - T), __expf(a.w - T));
        w.z = pk2(__expf(d.x - T), __expf(d.y - T));
        w.w = pk2(__expf(d.z - T), __expf(d.w - T));
        e_lds[i * 16 + (c ^ swz)] = w;   // XOR swizzle: 64-lane b128 reads spread over banks
    }

    // ---- phase 2: init y = onehot(start=510), r = 0 ----
    y_sh[i] = (i == NL - 2) ? (unsigned short)0x3C00u : (unsigned short)0u;
    float r = 0.0f;
    const float* lrow = logits + (size_t)b * NS * NL + i;
    __syncthreads();

    const uint4* y4   = (const uint4*)y_sh;
    const uint4* my_e = e_lds + i * 16;

    // ---- phase 3: scan over time ----
    for (int t = 0; t < len; ++t) {
        float lg = lrow[(size_t)t * NL];      // issued early, hidden under dot loop
        float s0 = 0.f, s1 = 0.f, s2 = 0.f, s3 = 0.f;
        #pragma unroll
        for (int c = 0; c < 48; ++c) {        // register part: cols 0..383
            uint4 yw = y4[c];                 // broadcast LDS read, 8 f16 y values
            s0 = dot2acc(Ereg[4 * c + 0], yw.x, s0);
            s1 = dot2acc(Ereg[4 * c + 1], yw.y, s1);
            s2 = dot2acc(Ereg[4 * c + 2], yw.z, s2);
            s3 = dot2acc(Ereg[4 * c + 3], yw.w, s3);
        }
        #pragma unroll
        for (int c = 0; c < 16; ++c) {        // LDS part: cols 384..511
            uint4 ew = my_e[c ^ swz];
            uint4 yw = y4[48 + c];
            s0 = dot2acc(ew.x, yw.x, s0);
            s1 = dot2acc(ew.y, yw.y, s1);
            s2 = dot2acc(ew.z, yw.z, s2);
            s3 = dot2acc(ew.w, yw.w, s3);
        }
        float v = ((s0 + s1) + (s2 + s3)) * __expf(lg);

        // block max of v -> cmax
        float mv = v;
        #pragma unroll
        for (int off = 32; off; off >>= 1) mv = fmaxf(mv, __shfl_xor(mv, off));
        if (lane == 0) red[wid] = mv;
        __syncthreads();                      // also guarantees all y reads done
        float cmax = red[0];
        #pragma unroll
        for (int k = 1; k < 8; ++k) cmax = fmaxf(cmax, red[k]);

        float yn = v * (1.0f / cmax);
        y_sh[i] = __builtin_bit_cast(unsigned short, (_Float16)yn);
        r += T + __logf(cmax);
        __syncthreads();                      // y ready for next step
    }

    // ---- phase 4: out[b] = r + T + log( sum_i y_i * exp(trans[stop,i] - T) ) ----
    float yi;
    {
        _Float16 h = __builtin_bit_cast(_Float16, y_sh[i]);
        yi = (float)h;
    }
    float term = yi * __expf(trans[(size_t)(NL - 1) * NL + i] - T);
    #pragma unroll
    for (int off = 32; off; off >>= 1) term += __shfl_xor(term, off);
    if (lane == 0) red[wid] = term;
    __syncthreads();
    if (i == 0) {
        float tot = 0.f;
        #pragma unroll
        for (int k = 0; k < 8; ++k) tot += red[k];
        out[b] = r + T + __logf(tot);
    }
}

extern "C" void kernel_launch(void* const* d_in, const int* in_sizes, int n_in,
                              void* d_out, int out_size, void* d_ws, size_t ws_size,
                              hipStream_t stream) {
    const float* logits = (const float*)d_in[0];
    const int*   lens   = (const int*)d_in[1];
    const float* trans  = (const float*)d_in[2];
    float*       out    = (float*)d_out;

    // >64KB dynamic LDS requires opting in (idempotent; same work every call)
    hipFuncSetAttribute(reinterpret_cast<const void*>(crf_fwd_kernel),
                        hipFuncAttributeMaxDynamicSharedMemorySize, SMEM_TOTAL);

    crf_fwd_kernel<<<dim3(NB), dim3(512), SMEM_TOTAL, stream>>>(logits, lens, trans, out);
}